// Round 6
// baseline (636.602 us; speedup 1.0000x reference)
//
#include <hip/hip_runtime.h>
#include <stdint.h>

#define Bn 2048
#define Tn 512
#define An 32
#define Hn 16

typedef __attribute__((ext_vector_type(8))) short bf16x8;
typedef __attribute__((ext_vector_type(4))) float f32x4;
typedef __attribute__((ext_vector_type(2))) unsigned int uintx2;

union FragU { bf16x8 v; uint32_t u[4]; };

static __device__ __forceinline__ uint32_t pack_hi16(float a, float b){
  return (__float_as_uint(b) & 0xFFFF0000u) | (__float_as_uint(a) >> 16);
}
// split 8 fp32 into hi/lo bf16 fragments (element e = k index e; even k low half of dword)
static __device__ __forceinline__ void split8(const float* s, FragU& hi, FragU& lo){
#pragma unroll
  for (int d = 0; d < 4; ++d){
    float a = s[2*d], b = s[2*d+1];
    float ah = __uint_as_float(__float_as_uint(a) & 0xFFFF0000u);
    float bh = __uint_as_float(__float_as_uint(b) & 0xFFFF0000u);
    hi.u[d] = pack_hi16(a, b);
    lo.u[d] = pack_hi16(a - ah, b - bh);
  }
}
static __device__ __forceinline__ f32x4 MF(const FragU& a, const FragU& b, f32x4 c){
  return __builtin_amdgcn_mfma_f32_16x16x32_bf16(a.v, b.v, c, 0, 0, 0);
}
// pack h into {bf16(h - bf16hi(h)) , bf16hi(h)} in one perm
static __device__ __forceinline__ uint32_t packPair(float h){
  float hh = __uint_as_float(__float_as_uint(h) & 0xFFFF0000u);
  float lo = h - hh;
  return __builtin_amdgcn_perm(__float_as_uint(lo), __float_as_uint(h), 0x07060302u);
}

// ---- permlane swap helpers (value-semantic builtins: no register aliasing) ----
// pl32(v) -> x = v[l&31], y = v[32|(l&31)]
static __device__ __forceinline__ void pl32(uint32_t v, uint32_t& x, uint32_t& y){
#if __has_builtin(__builtin_amdgcn_permlane32_swap)
  uintx2 s = __builtin_amdgcn_permlane32_swap(v, v, false, false);
  x = s[0]; y = s[1];
#else
  uint32_t a = v, b = v;
  asm volatile("v_permlane32_swap_b32 %0, %1" : "+v"(a), "+&v"(b));
  x = a; y = b;
#endif
}
// pl16(v) -> x = v[l&~16], y = v[l|16]
static __device__ __forceinline__ void pl16(uint32_t v, uint32_t& x, uint32_t& y){
#if __has_builtin(__builtin_amdgcn_permlane16_swap)
  uintx2 s = __builtin_amdgcn_permlane16_swap(v, v, false, false);
  x = s[0]; y = s[1];
#else
  uint32_t a = v, b = v;
  asm volatile("v_permlane16_swap_b32 %0, %1" : "+v"(a), "+&v"(b));
  x = a; y = b;
#endif
}

// rebuild B1 = [h_hi (k=0..15) ; h_lo (k=16..31)] via permlane swaps (no DS pipe).
// grp g lane-group value: pk of lane g*16 + n.  P=grp (q&1)*2, Q=grp (q&1)*2+1.
static __device__ __forceinline__ void buildB1perm(const uint32_t* pk, bool qodd,
                                                   uint32_t bsel, FragU& B1){
  uint32_t P[4], Q[4];
#pragma unroll
  for (int r = 0; r < 4; ++r){
    uint32_t lo32, hi32; pl32(pk[r], lo32, hi32);   // pk[l&31], pk[32|(l&31)]
    uint32_t g0, g1;     pl16(lo32, g0, g1);        // grp0, grp1
    uint32_t g2, g3;     pl16(hi32, g2, g3);        // grp2, grp3
    P[r] = qodd ? g2 : g0;
    Q[r] = qodd ? g3 : g1;
  }
  B1.u[0] = __builtin_amdgcn_perm(P[1], P[0], bsel);
  B1.u[1] = __builtin_amdgcn_perm(P[3], P[2], bsel);
  B1.u[2] = __builtin_amdgcn_perm(Q[1], Q[0], bsel);
  B1.u[3] = __builtin_amdgcn_perm(Q[3], Q[2], bsel);
}

// known-correct fallback: DS bpermute (R3 path, verified passing)
static __device__ __forceinline__ void buildB1ds(const uint32_t* pk, int srcA, int srcB,
                                                 uint32_t bsel, FragU& B1){
  uint32_t d0 = (uint32_t)__builtin_amdgcn_ds_bpermute(srcA, (int)pk[0]);
  uint32_t d1 = (uint32_t)__builtin_amdgcn_ds_bpermute(srcA, (int)pk[1]);
  uint32_t d2 = (uint32_t)__builtin_amdgcn_ds_bpermute(srcA, (int)pk[2]);
  uint32_t d3 = (uint32_t)__builtin_amdgcn_ds_bpermute(srcA, (int)pk[3]);
  uint32_t d4 = (uint32_t)__builtin_amdgcn_ds_bpermute(srcB, (int)pk[0]);
  uint32_t d5 = (uint32_t)__builtin_amdgcn_ds_bpermute(srcB, (int)pk[1]);
  uint32_t d6 = (uint32_t)__builtin_amdgcn_ds_bpermute(srcB, (int)pk[2]);
  uint32_t d7 = (uint32_t)__builtin_amdgcn_ds_bpermute(srcB, (int)pk[3]);
  B1.u[0] = __builtin_amdgcn_perm(d1, d0, bsel);
  B1.u[1] = __builtin_amdgcn_perm(d3, d2, bsel);
  B1.u[2] = __builtin_amdgcn_perm(d5, d4, bsel);
  B1.u[3] = __builtin_amdgcn_perm(d7, d6, bsel);
}

// Single-wave-per-tile LSTM. No LDS, no barriers.
// Chain per step: B1 -> h-MFMAs (independent) -> gate FMA -> exp2/rcp -> c2k
//                 -> exp2/rcp -> h -> pack -> exchange -> B1.
// x-part (12 MFMAs) pipelined one step ahead: off the chain.
__global__ __launch_bounds__(64, 1)
void lstm_fused(const float* __restrict__ xin,   // [B,T,32]
                const float* __restrict__ masks, // [B,T]
                const float* __restrict__ h0,    // [B,16]
                const float* __restrict__ c0,    // [B,16]
                const float* __restrict__ w_ih,  // [64,32]
                const float* __restrict__ w_hh,  // [64,16]
                const float* __restrict__ b_ih,  // [64]
                const float* __restrict__ b_hh,  // [64]
                const float* __restrict__ w_act, // [32,16]
                const float* __restrict__ b_act, // [32]
                const float* __restrict__ w_cr,  // [16]
                const float* __restrict__ b_cr,  // [1]
                float* __restrict__ actor,       // [B,T,32]
                float* __restrict__ critic,      // [B,T]
                float* __restrict__ hT,          // [B,16]
                float* __restrict__ cT)          // [B,16]
{
  const int l = threadIdx.x;           // 0..63
  const int q = l >> 4;
  const int n = l & 15;
  const int b0 = blockIdx.x * 16;
  const int colbase = (q & 1) * 8;
  const bool hiQuad = (q < 2);
  const bool qodd = (q & 1) != 0;
  const uint32_t bsel = hiQuad ? 0x05040100u : 0x07060302u;

  const float KS = -1.44269504088896f; // sigmoid gates: sigm(x)=rcp(1+exp2(KS*x))
  const float KG =  2.88539008177793f; // tanh gate:     tanh(x)=1-2*rcp(1+exp2(KG*x))
  const float invKG = 0.346573590279973f; // 1/KG

  // ---- probe the permlane network once; fall back to bpermute if convention differs ----
  bool permOK;
  {
    uint32_t v = (uint32_t)l;
    uint32_t x32, y32; pl32(v, x32, y32);
    uint32_t x16, y16; pl16(v, x16, y16);
    bool ok = (x32 == (uint32_t)(l & 31)) && (y32 == (uint32_t)(32 | (l & 31))) &&
              (x16 == (uint32_t)(l & ~16)) && (y16 == (uint32_t)(l | 16));
    permOK = __all(ok);
  }

  // ---- per-gate weight fragments, pre-scaled; A1=[Whi|Whi], A2=[Wlo|0] ----
  FragU wihH0, wihL0, whh10, whh20; f32x4 bias0;
  FragU wihH1, wihL1, whh11, whh21; f32x4 bias1;
  FragU wihH2, wihL2, whh12, whh22; f32x4 bias2;
  FragU wihH3, wihL3, whh13, whh23; f32x4 bias3;
  {
    auto loadGate = [&](int g, float sc, FragU& wh, FragU& wl, FragU& a1, FragU& a2, f32x4& bg){
      float tmp[8];
#pragma unroll
      for (int j = 0; j < 8; ++j) tmp[j] = w_ih[(g*16 + n)*32 + q*8 + j] * sc;
      split8(tmp, wh, wl);
#pragma unroll
      for (int j = 0; j < 8; ++j) tmp[j] = w_hh[(g*16 + n)*16 + colbase + j] * sc;
      FragU hh, hl; split8(tmp, hh, hl);
#pragma unroll
      for (int d = 0; d < 4; ++d){
        a1.u[d] = hh.u[d];                     // [Whi | Whi]
        a2.u[d] = hiQuad ? hl.u[d] : 0u;       // [Wlo | 0]
      }
#pragma unroll
      for (int r = 0; r < 4; ++r)
        bg[r] = (b_ih[g*16 + q*4 + r] + b_hh[g*16 + q*4 + r]) * sc;
    };
    loadGate(0, KS, wihH0, wihL0, whh10, whh20, bias0);  // i
    loadGate(1, KS, wihH1, wihL1, whh11, whh21, bias1);  // f
    loadGate(2, KG, wihH2, wihL2, whh12, whh22, bias2);  // g (tanh)
    loadGate(3, KS, wihH3, wihL3, whh13, whh23, bias3);  // o
  }

  // ---- head weights (actor 2 tiles + critic), unscaled, same A1/A2 pattern ----
  FragU whA10, whA20, whA11, whA21, wcA1, wcA2;
  f32x4 biasA0, biasA1;
  const float bcr = b_cr[0];
  {
    float tmp[8];
#pragma unroll
    for (int j = 0; j < 8; ++j) tmp[j] = w_act[(0*16 + n)*16 + colbase + j];
    { FragU hh, hl; split8(tmp, hh, hl);
#pragma unroll
      for (int d = 0; d < 4; ++d){ whA10.u[d] = hh.u[d]; whA20.u[d] = hiQuad ? hl.u[d] : 0u; } }
#pragma unroll
    for (int r = 0; r < 4; ++r) biasA0[r] = b_act[0*16 + q*4 + r];
#pragma unroll
    for (int j = 0; j < 8; ++j) tmp[j] = w_act[(1*16 + n)*16 + colbase + j];
    { FragU hh, hl; split8(tmp, hh, hl);
#pragma unroll
      for (int d = 0; d < 4; ++d){ whA11.u[d] = hh.u[d]; whA21.u[d] = hiQuad ? hl.u[d] : 0u; } }
#pragma unroll
    for (int r = 0; r < 4; ++r) biasA1[r] = b_act[1*16 + q*4 + r];
#pragma unroll
    for (int j = 0; j < 8; ++j) tmp[j] = (n == 0) ? w_cr[colbase + j] : 0.0f;
    { FragU hh, hl; split8(tmp, hh, hl);
#pragma unroll
      for (int d = 0; d < 4; ++d){ wcA1.u[d] = hh.u[d]; wcA2.u[d] = hiQuad ? hl.u[d] : 0u; } }
  }

  const int srcA = (((q & 1) * 2) * 16 + n) * 4;
  const int srcB = srcA + 64;

  // ---- initial state (lane-local: rows q*4+r, batch n) ----
  float cs[4], hs[4];
#pragma unroll
  for (int r = 0; r < 4; ++r){
    hs[r] = h0[(b0 + n)*16 + q*4 + r];
    cs[r] = c0[(b0 + n)*16 + q*4 + r];
  }
  uint32_t pk[4];
#pragma unroll
  for (int r = 0; r < 4; ++r) pk[r] = packPair(hs[r]);
  FragU B1;

  const f32x4 zero4 = {0.f, 0.f, 0.f, 0.f};

  // ---- x prefetch: depth-4 rotating register queue ----
  const size_t xrow = (size_t)(b0 + n) * Tn * 32 + q * 8;
  float4 xA[4], xB[4];
#pragma unroll
  for (int u = 0; u < 4; ++u){
    xA[u] = *(const float4*)&xin[xrow + (size_t)u * 32];
    xB[u] = *(const float4*)&xin[xrow + (size_t)u * 32 + 4];
  }
  const size_t mrow = (size_t)(b0 + n) * Tn;
  float4 mQ0 = *(const float4*)&masks[mrow];

  // x-part (12 MFMAs) helper: ax = W_ih * x + bias, all 4 gates
  auto computeAx = [&](const float4& va, const float4& vb, f32x4* ax){
    float s[8] = {va.x, va.y, va.z, va.w, vb.x, vb.y, vb.z, vb.w};
    FragU Xh, Xl; split8(s, Xh, Xl);
    ax[0] = MF(wihH0, Xh, bias0); ax[0] = MF(wihH0, Xl, ax[0]); ax[0] = MF(wihL0, Xh, ax[0]);
    ax[1] = MF(wihH1, Xh, bias1); ax[1] = MF(wihH1, Xl, ax[1]); ax[1] = MF(wihL1, Xh, ax[1]);
    ax[2] = MF(wihH2, Xh, bias2); ax[2] = MF(wihH2, Xl, ax[2]); ax[2] = MF(wihL2, Xh, ax[2]);
    ax[3] = MF(wihH3, Xh, bias3); ax[3] = MF(wihH3, Xl, ax[3]); ax[3] = MF(wihL3, Xh, ax[3]);
  };

  // ---- main loop, parameterized on the exchange implementation ----
  auto mainLoop = [&](auto rebuild){
    rebuild(pk, B1);                      // B1 = h0
    f32x4 axP[4];
    computeAx(xA[0], xB[0], axP);         // ax for t=0
    float4 mQ = mQ0;

    for (int t0 = 0; t0 < Tn; t0 += 4){
      const int tb = (t0 + 4 < Tn) ? (t0 + 4) : 0;
      float4 mN = *(const float4*)&masks[mrow + tb];
#pragma unroll
      for (int u = 0; u < 4; ++u){
        const int t = t0 + u;
        const float m = (u == 0) ? mQ.x : (u == 1) ? mQ.y : (u == 2) ? mQ.z : mQ.w;
        float cmk[4];                     // KG * c * m, off the post-activation chain
#pragma unroll
        for (int r = 0; r < 4; ++r) cmk[r] = (cs[r] * m) * KG;

        // h-part: 8 INDEPENDENT MFMAs on B1 (no accumulate chains)
        f32x4 ah0a = MF(whh10, B1, zero4), ah0b = MF(whh20, B1, zero4);
        f32x4 ah1a = MF(whh11, B1, zero4), ah1b = MF(whh21, B1, zero4);
        f32x4 ah2a = MF(whh12, B1, zero4), ah2b = MF(whh22, B1, zero4);
        f32x4 ah3a = MF(whh13, B1, zero4), ah3b = MF(whh23, B1, zero4);

        // heads for step t-1 (B1 still holds h_{t-1})
        f32x4 a0, a1, cc;
        if (t){
          a0 = MF(whA10, B1, biasA0); a0 = MF(whA20, B1, a0);
          a1 = MF(whA11, B1, biasA1); a1 = MF(whA21, B1, a1);
          cc = MF(wcA1, B1, zero4);   cc = MF(wcA2, B1, cc);
        }

        // x-part for NEXT step (t+1) — stall filler, never on the chain
        f32x4 axN[4];
        {
          const int s2 = (u + 1) & 3;     // slot holding x(t+1)
          computeAx(xA[s2], xB[s2], axN);
        }
        // refill slot u with x(t+4)
        {
          const int tn = (t + 4 < Tn) ? (t + 4) : t;
          xA[u] = *(const float4*)&xin[xrow + (size_t)tn * 32];
          xB[u] = *(const float4*)&xin[xrow + (size_t)tn * 32 + 4];
        }
        // head stores (issued late so head MFMAs have completed)
        if (t){
          const int th = t - 1;
          *(f32x4*)&actor[((size_t)(b0 + n) * Tn + th) * 32 + 0*16 + q*4] = a0;
          *(f32x4*)&actor[((size_t)(b0 + n) * Tn + th) * 32 + 1*16 + q*4] = a1;
          if (q == 0) critic[(size_t)(b0 + n) * Tn + th] = cc[0] + bcr;
        }

        // activation + state update, per-r interleaved chains
#pragma unroll
        for (int r = 0; r < 4; ++r){
          float gi = m * ah0b[r] + axP[0][r]; gi = m * ah0a[r] + gi;
          float gf = m * ah1b[r] + axP[1][r]; gf = m * ah1a[r] + gf;
          float gg = m * ah2b[r] + axP[2][r]; gg = m * ah2a[r] + gg;
          float go = m * ah3b[r] + axP[3][r]; go = m * ah3a[r] + go;
          float iv = __builtin_amdgcn_rcpf(1.0f + __builtin_amdgcn_exp2f(gi));
          float fv = __builtin_amdgcn_rcpf(1.0f + __builtin_amdgcn_exp2f(gf));
          float gr = __builtin_amdgcn_rcpf(1.0f + __builtin_amdgcn_exp2f(gg));
          float ov = __builtin_amdgcn_rcpf(1.0f + __builtin_amdgcn_exp2f(go));
          float gvk = gr * (-2.0f * KG) + KG;  // KG * tanh(g)
          float c2k = iv * gvk + fv * cmk[r];  // KG * c2
          cs[r] = c2k * invKG;                 // c2 (off-chain use next step)
          float et = __builtin_amdgcn_rcpf(1.0f + __builtin_amdgcn_exp2f(c2k));
          float hv = ov - 2.0f * (ov * et);    // ov * tanh(c2)
          hs[r] = hv;
          pk[r] = packPair(hv);
        }
        rebuild(pk, B1);                   // exchange -> B1 = h_t
#pragma unroll
        for (int g = 0; g < 4; ++g) axP[g] = axN[g];
      }
      mQ = mN;
    }
  };

  if (permOK){
    mainLoop([&](const uint32_t* p, FragU& B){ buildB1perm(p, qodd, bsel, B); });
  } else {
    mainLoop([&](const uint32_t* p, FragU& B){ buildB1ds(p, srcA, srcB, bsel, B); });
  }

  // epilogue: heads for t = Tn-1
  {
    const int th = Tn - 1;
    f32x4 a0 = MF(whA10, B1, biasA0); a0 = MF(whA20, B1, a0);
    *(f32x4*)&actor[((size_t)(b0 + n) * Tn + th) * 32 + 0*16 + q*4] = a0;
    f32x4 a1 = MF(whA11, B1, biasA1); a1 = MF(whA21, B1, a1);
    *(f32x4*)&actor[((size_t)(b0 + n) * Tn + th) * 32 + 1*16 + q*4] = a1;
    f32x4 cc = MF(wcA1, B1, zero4); cc = MF(wcA2, B1, cc);
    if (q == 0) critic[(size_t)(b0 + n) * Tn + th] = cc[0] + bcr;
  }
  *(float4*)&hT[(b0 + n)*16 + q*4] = make_float4(hs[0], hs[1], hs[2], hs[3]);
  *(float4*)&cT[(b0 + n)*16 + q*4] = make_float4(cs[0], cs[1], cs[2], cs[3]);
}

extern "C" void kernel_launch(void* const* d_in, const int* in_sizes, int n_in,
                              void* d_out, int out_size, void* d_ws, size_t ws_size,
                              hipStream_t stream) {
  (void)in_sizes; (void)n_in; (void)out_size; (void)d_ws; (void)ws_size;
  const float* xin   = (const float*)d_in[0];
  const float* masks = (const float*)d_in[1];
  const float* h0    = (const float*)d_in[2];
  const float* c0    = (const float*)d_in[3];
  const float* w_ih  = (const float*)d_in[4];
  const float* w_hh  = (const float*)d_in[5];
  const float* b_ih  = (const float*)d_in[6];
  const float* b_hh  = (const float*)d_in[7];
  const float* w_act = (const float*)d_in[8];
  const float* b_act = (const float*)d_in[9];
  const float* w_cr  = (const float*)d_in[10];
  const float* b_cr  = (const float*)d_in[11];

  float* out    = (float*)d_out;
  float* actor  = out;                                   // [B,T,32]
  float* critic = out + (size_t)Bn * Tn * An;            // [B,T]
  float* hT     = critic + (size_t)Bn * Tn;              // [B,16]
  float* cT     = hT + (size_t)Bn * Hn;                  // [B,16]

  lstm_fused<<<Bn/16, 64, 0, stream>>>(xin, masks, h0, c0, w_ih, w_hh, b_ih, b_hh,
                                       w_act, b_act, w_cr, b_cr,
                                       actor, critic, hT, cT);
}

// Round 7
// 480.840 us; speedup vs baseline: 1.3239x; 1.3239x over previous
//
#include <hip/hip_runtime.h>
#include <stdint.h>

#define Bn 2048
#define Tn 512
#define An 32
#define Hn 16

typedef __attribute__((ext_vector_type(8))) short bf16x8;
typedef __attribute__((ext_vector_type(4))) float f32x4;

union FragU { bf16x8 v; uint32_t u[4]; };

static __device__ __forceinline__ uint32_t pack_hi16(float a, float b){
  return (__float_as_uint(b) & 0xFFFF0000u) | (__float_as_uint(a) >> 16);
}
// split 8 fp32 into hi/lo bf16 fragments (element e = k index e; even k low half of dword)
static __device__ __forceinline__ void split8(const float* s, FragU& hi, FragU& lo){
#pragma unroll
  for (int d = 0; d < 4; ++d){
    float a = s[2*d], b = s[2*d+1];
    float ah = __uint_as_float(__float_as_uint(a) & 0xFFFF0000u);
    float bh = __uint_as_float(__float_as_uint(b) & 0xFFFF0000u);
    hi.u[d] = pack_hi16(a, b);
    lo.u[d] = pack_hi16(a - ah, b - bh);
  }
}
static __device__ __forceinline__ uint32_t plo(uint32_t e, uint32_t o){
  return __builtin_amdgcn_perm(o, e, 0x05040100u);
}
static __device__ __forceinline__ f32x4 MF(const FragU& a, const FragU& b, f32x4 c){
  return __builtin_amdgcn_mfma_f32_16x16x32_bf16(a.v, b.v, c, 0, 0, 0);
}
// rebuild BHh = [h_bf16 | h_bf16] (duplicated halves) from per-lane packed state
// via wave-wide bpermute. pk[r] = bf16(h_row r) in low 16 bits.
static __device__ __forceinline__ void buildBHh(const uint32_t* pk, int srcA, int srcB,
                                                FragU& BHh){
  uint32_t d0 = (uint32_t)__builtin_amdgcn_ds_bpermute(srcA, (int)pk[0]);
  uint32_t d1 = (uint32_t)__builtin_amdgcn_ds_bpermute(srcA, (int)pk[1]);
  uint32_t d2 = (uint32_t)__builtin_amdgcn_ds_bpermute(srcA, (int)pk[2]);
  uint32_t d3 = (uint32_t)__builtin_amdgcn_ds_bpermute(srcA, (int)pk[3]);
  uint32_t d4 = (uint32_t)__builtin_amdgcn_ds_bpermute(srcB, (int)pk[0]);
  uint32_t d5 = (uint32_t)__builtin_amdgcn_ds_bpermute(srcB, (int)pk[1]);
  uint32_t d6 = (uint32_t)__builtin_amdgcn_ds_bpermute(srcB, (int)pk[2]);
  uint32_t d7 = (uint32_t)__builtin_amdgcn_ds_bpermute(srcB, (int)pk[3]);
  BHh.u[0] = plo(d0, d1); BHh.u[1] = plo(d2, d3);
  BHh.u[2] = plo(d4, d5); BHh.u[3] = plo(d6, d7);
}

// Single-wave-per-tile LSTM (R1 structure). bf16-h recurrence:
// W*h approximated as (Whi+Wlo)*bf16(h) — one MFMA via A1=[Whi|Wlo], B=[h|h].
// Only the Whi*h_residual term is dropped (within absmax budget).
__global__ __launch_bounds__(64, 1)
void lstm_fused(const float* __restrict__ xin,   // [B,T,32]
                const float* __restrict__ masks, // [B,T]
                const float* __restrict__ h0,    // [B,16]
                const float* __restrict__ c0,    // [B,16]
                const float* __restrict__ w_ih,  // [64,32]
                const float* __restrict__ w_hh,  // [64,16]
                const float* __restrict__ b_ih,  // [64]
                const float* __restrict__ b_hh,  // [64]
                const float* __restrict__ w_act, // [32,16]
                const float* __restrict__ b_act, // [32]
                const float* __restrict__ w_cr,  // [16]
                const float* __restrict__ b_cr,  // [1]
                float* __restrict__ actor,       // [B,T,32]
                float* __restrict__ critic,      // [B,T]
                float* __restrict__ hT,          // [B,16]
                float* __restrict__ cT)          // [B,16]
{
  const int l = threadIdx.x;           // 0..63
  const int q = l >> 4;
  const int n = l & 15;
  const int b0 = blockIdx.x * 16;
  const int colbase = (q & 1) * 8;

  const float KS = -1.44269504088896f; // sigmoid gates: sigm(x)=rcp(1+exp2(KS*x))
  const float KG =  2.88539008177793f; // tanh gate:     tanh(x)=1-2*rcp(1+exp2(KG*x))

  // ---- per-gate weight fragments (all 4 gates in this wave), pre-scaled ----
  // x-part: exact hi/lo split (12 MFMAs, off-chain filler).
  // h-part: single A1=[Whi|Wlo] fragment (acts on duplicated bf16 h).
  FragU wihH0, wihL0, whhA0; f32x4 bias0;
  FragU wihH1, wihL1, whhA1; f32x4 bias1;
  FragU wihH2, wihL2, whhA2; f32x4 bias2;
  FragU wihH3, wihL3, whhA3; f32x4 bias3;
  {
    auto loadGate = [&](int g, float sc, FragU& wh, FragU& wl, FragU& a1, f32x4& bg){
      float tmp[8];
#pragma unroll
      for (int j = 0; j < 8; ++j) tmp[j] = w_ih[(g*16 + n)*32 + q*8 + j] * sc;
      split8(tmp, wh, wl);
#pragma unroll
      for (int j = 0; j < 8; ++j) tmp[j] = w_hh[(g*16 + n)*16 + colbase + j] * sc;
      FragU hh, hl; split8(tmp, hh, hl);
#pragma unroll
      for (int d = 0; d < 4; ++d)
        a1.u[d] = (q < 2) ? hh.u[d] : hl.u[d];   // [Whh_hi | Whh_lo]
#pragma unroll
      for (int r = 0; r < 4; ++r)
        bg[r] = (b_ih[g*16 + q*4 + r] + b_hh[g*16 + q*4 + r]) * sc;
    };
    loadGate(0, KS, wihH0, wihL0, whhA0, bias0);  // i
    loadGate(1, KS, wihH1, wihL1, whhA1, bias1);  // f
    loadGate(2, KG, wihH2, wihL2, whhA2, bias2);  // g (tanh)
    loadGate(3, KS, wihH3, wihL3, whhA3, bias3);  // o
  }
  // head weights: single-fragment form as well
  FragU whA0, whA1f, wcA;
  f32x4 biasA0, biasA1;
  const float bcr = b_cr[0];
  {
    float tmp[8];
#pragma unroll
    for (int j = 0; j < 8; ++j) tmp[j] = w_act[(0*16 + n)*16 + colbase + j];
    { FragU hh, hl; split8(tmp, hh, hl);
#pragma unroll
      for (int d = 0; d < 4; ++d) whA0.u[d] = (q < 2) ? hh.u[d] : hl.u[d]; }
#pragma unroll
    for (int r = 0; r < 4; ++r) biasA0[r] = b_act[0*16 + q*4 + r];
#pragma unroll
    for (int j = 0; j < 8; ++j) tmp[j] = w_act[(1*16 + n)*16 + colbase + j];
    { FragU hh, hl; split8(tmp, hh, hl);
#pragma unroll
      for (int d = 0; d < 4; ++d) whA1f.u[d] = (q < 2) ? hh.u[d] : hl.u[d]; }
#pragma unroll
    for (int r = 0; r < 4; ++r) biasA1[r] = b_act[1*16 + q*4 + r];
#pragma unroll
    for (int j = 0; j < 8; ++j) tmp[j] = (n == 0) ? w_cr[colbase + j] : 0.0f;
    { FragU hh, hl; split8(tmp, hh, hl);
#pragma unroll
      for (int d = 0; d < 4; ++d) wcA.u[d] = (q < 2) ? hh.u[d] : hl.u[d]; }
  }

  const int srcA = (((q & 1) * 2) * 16 + n) * 4;
  const int srcB = srcA + 64;

  // ---- initial state (lane-local: rows q*4+r, batch n) ----
  float cs[4], hs[4];
#pragma unroll
  for (int r = 0; r < 4; ++r){
    hs[r] = h0[(b0 + n)*16 + q*4 + r];
    cs[r] = c0[(b0 + n)*16 + q*4 + r];
  }
  uint32_t pk[4];
#pragma unroll
  for (int r = 0; r < 4; ++r) pk[r] = __float_as_uint(hs[r]) >> 16;  // bf16(h)
  FragU BHh;
  buildBHh(pk, srcA, srcB, BHh);

  const f32x4 zero4 = {0.f, 0.f, 0.f, 0.f};

  // ---- x prefetch: depth-4 rotating register queue ----
  const size_t xrow = (size_t)(b0 + n) * Tn * 32 + q * 8;
  float4 xA[4], xB[4];
#pragma unroll
  for (int u = 0; u < 4; ++u){
    xA[u] = *(const float4*)&xin[xrow + (size_t)u * 32];
    xB[u] = *(const float4*)&xin[xrow + (size_t)u * 32 + 4];
  }
  // masks: one float4 per 4 steps, prefetched one group ahead
  const size_t mrow = (size_t)(b0 + n) * Tn;
  float4 mQ = *(const float4*)&masks[mrow];

  for (int t0 = 0; t0 < Tn; t0 += 4){
    const int tb = (t0 + 4 < Tn) ? (t0 + 4) : 0;
    float4 mN = *(const float4*)&masks[mrow + tb];
#pragma unroll
    for (int u = 0; u < 4; ++u){
      const int t = t0 + u;
      const float m = (u == 0) ? mQ.x : (u == 1) ? mQ.y : (u == 2) ? mQ.z : mQ.w;

      // x fragment for this step
      FragU Xh, Xl;
      {
        float s[8] = {xA[u].x, xA[u].y, xA[u].z, xA[u].w,
                      xB[u].x, xB[u].y, xB[u].z, xB[u].w};
        split8(s, Xh, Xl);
      }
      {
        const int tn = (t + 4 < Tn) ? (t + 4) : t;
        xA[u] = *(const float4*)&xin[xrow + (size_t)tn * 32];
        xB[u] = *(const float4*)&xin[xrow + (size_t)tn * 32 + 4];
      }

      // x-part MFMAs (12): issue first — cover bpermute latency from prev step
      f32x4 ax0 = MF(wihH0, Xh, bias0); ax0 = MF(wihH0, Xl, ax0); ax0 = MF(wihL0, Xh, ax0);
      f32x4 ax1 = MF(wihH1, Xh, bias1); ax1 = MF(wihH1, Xl, ax1); ax1 = MF(wihL1, Xh, ax1);
      f32x4 ax2 = MF(wihH2, Xh, bias2); ax2 = MF(wihH2, Xl, ax2); ax2 = MF(wihL2, Xh, ax2);
      f32x4 ax3 = MF(wihH3, Xh, bias3); ax3 = MF(wihH3, Xl, ax3);

      // h-part MFMAs (4, single each): the recurrent dependency
      f32x4 ah0 = MF(whhA0, BHh, zero4);
      f32x4 ah1 = MF(whhA1, BHh, zero4);
      f32x4 ah2 = MF(whhA2, BHh, zero4);
      f32x4 ah3 = MF(whhA3, BHh, zero4);

      // heads for step t-1 (BHh still holds h_{t-1}); fills ah-MFMA shadow
      if (t){
        const int th = t - 1;
        f32x4 a0 = MF(whA0, BHh, biasA0);
        __builtin_nontemporal_store(a0,
            (f32x4*)&actor[((size_t)(b0 + n) * Tn + th) * 32 + 0*16 + q*4]);
        f32x4 a1 = MF(whA1f, BHh, biasA1);
        __builtin_nontemporal_store(a1,
            (f32x4*)&actor[((size_t)(b0 + n) * Tn + th) * 32 + 1*16 + q*4]);
        f32x4 cc = MF(wcA, BHh, zero4);
        if (q == 0)
          __builtin_nontemporal_store(cc[0] + bcr,
              &critic[(size_t)(b0 + n) * Tn + th]);
      }

      // activation + state update, per-r interleaved chains (R1 form)
#pragma unroll
      for (int r = 0; r < 4; ++r){
        float gi = ax0[r] + m * ah0[r];
        float gf = ax1[r] + m * ah1[r];
        float gg = ax2[r] + m * ah2[r];
        float go = ax3[r] + m * ah3[r];
        float iv = __builtin_amdgcn_rcpf(1.0f + __builtin_amdgcn_exp2f(gi));
        float fv = __builtin_amdgcn_rcpf(1.0f + __builtin_amdgcn_exp2f(gf));
        float gr = __builtin_amdgcn_rcpf(1.0f + __builtin_amdgcn_exp2f(gg));
        float ov = __builtin_amdgcn_rcpf(1.0f + __builtin_amdgcn_exp2f(go));
        float gv = 1.0f - 2.0f * gr;           // tanh(g)
        float c2 = fv * (cs[r] * m) + iv * gv;
        float et = __builtin_amdgcn_rcpf(1.0f + __builtin_amdgcn_exp2f(c2 * KG));
        float h2 = ov - 2.0f * (ov * et);      // ov * tanh(c2)
        cs[r] = c2;
        hs[r] = h2;
        pk[r] = __float_as_uint(h2) >> 16;     // bf16(h) — single shift pack
      }
      buildBHh(pk, srcA, srcB, BHh);           // latency covered by next step's ax block
    }
    mQ = mN;
  }

  // epilogue: heads for t = Tn-1
  {
    const int th = Tn - 1;
    f32x4 a0 = MF(whA0, BHh, biasA0);
    __builtin_nontemporal_store(a0,
        (f32x4*)&actor[((size_t)(b0 + n) * Tn + th) * 32 + 0*16 + q*4]);
    f32x4 a1 = MF(whA1f, BHh, biasA1);
    __builtin_nontemporal_store(a1,
        (f32x4*)&actor[((size_t)(b0 + n) * Tn + th) * 32 + 1*16 + q*4]);
    f32x4 cc = MF(wcA, BHh, zero4);
    if (q == 0)
      __builtin_nontemporal_store(cc[0] + bcr, &critic[(size_t)(b0 + n) * Tn + th]);
  }
  *(float4*)&hT[(b0 + n)*16 + q*4] = make_float4(hs[0], hs[1], hs[2], hs[3]);
  *(float4*)&cT[(b0 + n)*16 + q*4] = make_float4(cs[0], cs[1], cs[2], cs[3]);
}

extern "C" void kernel_launch(void* const* d_in, const int* in_sizes, int n_in,
                              void* d_out, int out_size, void* d_ws, size_t ws_size,
                              hipStream_t stream) {
  (void)in_sizes; (void)n_in; (void)out_size; (void)d_ws; (void)ws_size;
  const float* xin   = (const float*)d_in[0];
  const float* masks = (const float*)d_in[1];
  const float* h0    = (const float*)d_in[2];
  const float* c0    = (const float*)d_in[3];
  const float* w_ih  = (const float*)d_in[4];
  const float* w_hh  = (const float*)d_in[5];
  const float* b_ih  = (const float*)d_in[6];
  const float* b_hh  = (const float*)d_in[7];
  const float* w_act = (const float*)d_in[8];
  const float* b_act = (const float*)d_in[9];
  const float* w_cr  = (const float*)d_in[10];
  const float* b_cr  = (const float*)d_in[11];

  float* out    = (float*)d_out;
  float* actor  = out;                                   // [B,T,32]
  float* critic = out + (size_t)Bn * Tn * An;            // [B,T]
  float* hT     = critic + (size_t)Bn * Tn;              // [B,16]
  float* cT     = hT + (size_t)Bn * Hn;                  // [B,16]

  lstm_fused<<<Bn/16, 64, 0, stream>>>(xin, masks, h0, c0, w_ih, w_hh, b_ih, b_hh,
                                       w_act, b_act, w_cr, b_cr,
                                       actor, critic, hT, cT);
}